// Round 1
// baseline (114.602 us; speedup 1.0000x reference)
//
#include <hip/hip_runtime.h>

constexpr int POOL  = 7;
constexpr int GRIDS = 2;
constexpr float SCALE = 0.0625f;
constexpr int N_IMG = 4, C = 490, H = 100, W = 100;
constexpr int PLANE = H * W;                 // 10000 floats = 40 KB
constexpr int N16   = PLANE / 4;             // 2500 16-byte lane-transfers/plane
constexpr int NTHR  = 1024;                  // 16 waves
constexpr int NWAVE = NTHR / 64;
constexpr int MAX_IT = 2;                    // K <= NTHR*MAX_IT handled here

// ---- compute kernel: block = (c_in, img-pair p). 2 planes (80 KB) in LDS.
// Identical staging/compute structure to the 111.9us version, but stores
// out[k*C+c] DIRECTLY — no wsbuf, no transpose kernel, d_ws untouched.
// Rationale: the ws-poison fill (313.6 MB, ~48us) dominates the measured
// iteration; the scatter-store cost it was avoiding is only ~61 wave-store
// instructions per CU, and out (4 MB) fits in L2 for write-combining.
__global__ __launch_bounds__(NTHR) void psroi_pair_direct_kernel(
    const float* __restrict__ x, const float* __restrict__ rois,
    float* __restrict__ out, int K)
{
    __shared__ float plane2[2 * PLANE];      // 80000 B
    int bid  = blockIdx.x;
    int c_lo = bid & 7;
    int rest = bid >> 3;
    int p    = rest & 1;                     // image pair: {2p, 2p+1}
    int c_hi = rest >> 1;
    int c_in = c_hi * 8 + c_lo;
    if (c_in >= C) return;

    int lane = threadIdx.x & 63;
    int wave = threadIdx.x >> 6;

    // stage the pair's two planes via async global_load_lds width=16
#pragma unroll
    for (int i = 0; i < 2; ++i) {
        const float* src = x + ((size_t)(2 * p + i) * C + c_in) * PLANE;
        float* dstbase = plane2 + i * PLANE;
        for (int chunk = wave; chunk * 64 < N16; chunk += NWAVE) {
            int t16 = chunk * 64 + lane;
            if (t16 < N16) {
                __builtin_amdgcn_global_load_lds(
                    (const __attribute__((address_space(1))) void*)(src + t16 * 4),
                    (__attribute__((address_space(3))) void*)(dstbase + chunk * 256),
                    16, 0, 0);
            }
        }
    }

    // prefetch my ROI records while the DMA streams (no LDS dependence)
    float rp[MAX_IT][5];
    int nit = 0;
    for (int k = threadIdx.x; k < K && nit < MAX_IT; k += NTHR, ++nit) {
        const float* roi = rois + (size_t)k * 5;
        rp[nit][0] = roi[0]; rp[nit][1] = roi[1]; rp[nit][2] = roi[2];
        rp[nit][3] = roi[3]; rp[nit][4] = roi[4];
    }

    __syncthreads();   // drains vmcnt for LDS-bound loads

    int ph = (c_in / POOL) % POOL;           // block-uniform
    int pw = c_in % POOL;

    for (int it = 0; it < nit; ++it) {
        int k = threadIdx.x + it * NTHR;
        int img = (int)rp[it][0];
        if ((img >> 1) != p) continue;       // exec-masked; other pair-block handles it

        float rx1 = rp[it][1] * SCALE - 0.5f;
        float ry1 = rp[it][2] * SCALE - 0.5f;
        float rx2 = rp[it][3] * SCALE - 0.5f;
        float ry2 = rp[it][4] * SCALE - 0.5f;
        float bsh = (ry2 - ry1) * (1.0f / POOL);
        float bsw = (rx2 - rx1) * (1.0f / POOL);
        const float* pl = plane2 + (img & 1) * PLANE;

        int   rowlo[GRIDS], rowhi[GRIDS];
        float wyl[GRIDS], wyh[GRIDS];
        bool  vy[GRIDS];
        int   xlo[GRIDS], xhi[GRIDS];
        float wxl[GRIDS], wxh[GRIDS];
        bool  vx[GRIDS];
#pragma unroll
        for (int g = 0; g < GRIDS; ++g) {
            float yy = ry1 + ((float)ph + ((float)g + 0.5f) * (1.0f / GRIDS)) * bsh;
            vy[g] = (yy >= -1.0f) && (yy <= (float)H);
            float yc = fmaxf(yy, 0.0f);
            int lo = min((int)yc, H - 1);
            rowlo[g] = lo * W;
            rowhi[g] = min(lo + 1, H - 1) * W;
            float fy = (lo >= H - 1) ? 0.0f : (yc - (float)lo);
            wyl[g] = 1.0f - fy;  wyh[g] = fy;

            float xxv = rx1 + ((float)pw + ((float)g + 0.5f) * (1.0f / GRIDS)) * bsw;
            vx[g] = (xxv >= -1.0f) && (xxv <= (float)W);
            float xc = fmaxf(xxv, 0.0f);
            int lo2 = min((int)xc, W - 1);
            xlo[g] = lo2;
            xhi[g] = min(lo2 + 1, W - 1);
            float fx = (lo2 >= W - 1) ? 0.0f : (xc - (float)lo2);
            wxl[g] = 1.0f - fx;  wxh[g] = fx;
        }

        float acc = 0.0f;
#pragma unroll
        for (int gy = 0; gy < GRIDS; ++gy) {
#pragma unroll
            for (int gx = 0; gx < GRIDS; ++gx) {
                float v0 = pl[rowlo[gy] + xlo[gx]];
                float v1 = pl[rowlo[gy] + xhi[gx]];
                float v2 = pl[rowhi[gy] + xlo[gx]];
                float v3 = pl[rowhi[gy] + xhi[gx]];
                float w = (vy[gy] && vx[gx]) ? 0.25f : 0.0f;
                acc += w * (wyl[gy] * (wxl[gx] * v0 + wxh[gx] * v1)
                          + wyh[gy] * (wxl[gx] * v2 + wxh[gx] * v3));
            }
        }
        // direct scatter store: stride C floats across lanes. ~15.6K wave-store
        // instrs total; out (4 MB) is L2-resident for write-combining.
        out[(size_t)k * C + c_in] = acc;
    }
}

// ------------- fallback: direct-store kernel (any K) -------------
__global__ __launch_bounds__(256) void psroi_direct_kernel(
    const float* __restrict__ x, const float* __restrict__ rois,
    float* __restrict__ out, int K, int numKC)
{
    int bid  = blockIdx.x;
    int c_lo = bid & 7;
    int t    = bid >> 3;
    int kc   = t % numKC;
    int c_hi = t / numKC;
    int c_in = c_hi * 8 + c_lo;
    if (c_in >= C) return;
    int k = kc * 256 + (int)threadIdx.x;
    if (k >= K) return;

    int ph = (c_in / POOL) % POOL;
    int pw = c_in % POOL;
    const float* roi = rois + (size_t)k * 5;
    int   img = (int)roi[0];
    float rx1 = roi[1] * SCALE - 0.5f;
    float ry1 = roi[2] * SCALE - 0.5f;
    float rx2 = roi[3] * SCALE - 0.5f;
    float ry2 = roi[4] * SCALE - 0.5f;
    float bsh = (ry2 - ry1) * (1.0f / POOL);
    float bsw = (rx2 - rx1) * (1.0f / POOL);
    int off0 = (img * C + c_in) * PLANE;

    float acc = 0.0f;
#pragma unroll
    for (int gy = 0; gy < GRIDS; ++gy) {
        float yy = ry1 + ((float)ph + ((float)gy + 0.5f) * (1.0f / GRIDS)) * bsh;
        bool vy = (yy >= -1.0f) && (yy <= (float)H);
        float yc = fmaxf(yy, 0.0f);
        int lo = min((int)yc, H - 1);
        int rl = lo * W, rh = min(lo + 1, H - 1) * W;
        float fy = (lo >= H - 1) ? 0.0f : (yc - (float)lo);
#pragma unroll
        for (int gx = 0; gx < GRIDS; ++gx) {
            float xxv = rx1 + ((float)pw + ((float)gx + 0.5f) * (1.0f / GRIDS)) * bsw;
            bool vx = (xxv >= -1.0f) && (xxv <= (float)W);
            float xc = fmaxf(xxv, 0.0f);
            int lo2 = min((int)xc, W - 1);
            int xh = min(lo2 + 1, W - 1);
            float fx = (lo2 >= W - 1) ? 0.0f : (xc - (float)lo2);
            float w = (vy && vx) ? 0.25f : 0.0f;
            acc += w * ((1.0f - fy) * ((1.0f - fx) * x[off0 + rl + lo2] + fx * x[off0 + rl + xh])
                      + fy          * ((1.0f - fx) * x[off0 + rh + lo2] + fx * x[off0 + rh + xh]));
        }
    }
    out[(size_t)k * C + c_in] = acc;
}

extern "C" void kernel_launch(void* const* d_in, const int* in_sizes, int n_in,
                              void* d_out, int out_size, void* d_ws, size_t ws_size,
                              hipStream_t stream) {
    const float* x    = (const float*)d_in[0];
    const float* rois = (const float*)d_in[1];
    float* out = (float*)d_out;
    int K = in_sizes[1] / 5;                              // 2048

    (void)d_ws; (void)ws_size;                            // workspace deliberately unused

    if (K <= NTHR * MAX_IT) {
        int cGroups = (C + 7) / 8;                        // 62
        int blocks = cGroups * 2 * 8;                     // 992 (p interleaved mod 8)
        psroi_pair_direct_kernel<<<blocks, NTHR, 0, stream>>>(x, rois, out, K);
    } else {
        int numKC = (K + 255) / 256;
        int blocks = ((C + 7) / 8) * numKC * 8;
        psroi_direct_kernel<<<blocks, 256, 0, stream>>>(x, rois, out, K, numKC);
    }
}